// Round 2
// baseline (3045.370 us; speedup 1.0000x reference)
//
#include <hip/hip_runtime.h>
#include <hip/hip_bf16.h>
#include <cmath>

typedef __hip_bfloat16 bf16;
typedef __bf16 bf16x8 __attribute__((ext_vector_type(8)));
typedef __bf16 bf16x4 __attribute__((ext_vector_type(4)));
typedef float f32x4 __attribute__((ext_vector_type(4)));

typedef __attribute__((address_space(1))) void void_g;
typedef __attribute__((address_space(3))) void void_l;

#define SEQ 2048
#define DMODEL 1024
#define NHEAD 16
#define HDIM 64
#define DFF 4096
#define WINDOW 128
#define LN_EPS 1e-5f

__device__ __forceinline__ void gl_lds16(const bf16* g, bf16* l) {
    __builtin_amdgcn_global_load_lds((void_g*)(g), (void_l*)(l), 16, 0, 0);
}

// ---------------- f32 -> bf16 conversion (weights), 4 elems/thread ----------------
__global__ __launch_bounds__(256)
void cvt_bf16(const float* __restrict__ src, bf16* __restrict__ dst, int n4) {
    int i = blockIdx.x * 256 + threadIdx.x;
    if (i < n4) {
        float4 v = ((const float4*)src)[i];
        bf16x4 o;
        o[0] = (__bf16)v.x; o[1] = (__bf16)v.y; o[2] = (__bf16)v.z; o[3] = (__bf16)v.w;
        ((bf16x4*)dst)[i] = o;
    }
}

// ---------------- positional encoding add: f32 in -> bf16 out ----------------
__global__ __launch_bounds__(256)
void add_pe(const float* __restrict__ X, bf16* __restrict__ x) {
    int idx = blockIdx.x * 256 + threadIdx.x;     // over SEQ*DMODEL
    int s = idx >> 10, d = idx & 1023;
    float i2 = (float)(d & ~1);
    float div = expf(i2 * (-9.210340371976184f / 1024.0f));  // ln(10000)
    float ang = (float)s * div;
    float pe = (d & 1) ? cosf(ang) : sinf(ang);
    x[idx] = (bf16)(X[idx] + pe);
}

// ---------------- GEMM: C[M,N] = A[M,K] * W[N,K]^T + bias(f32), ACT=1 -> relu ----------------
// 128x128 tile, BK=32, 256 threads = 4 waves (2x2), each wave 64x64 via 4x4 mfma_16x16x32_bf16
template<int ACT>
__global__ __launch_bounds__(256)
void gemm_bt(const bf16* __restrict__ A, const bf16* __restrict__ W,
             const float* __restrict__ bias, bf16* __restrict__ C,
             int M, int N, int K)
{
    __shared__ __align__(16) bf16 As[128 * 32];
    __shared__ __align__(16) bf16 Ws[128 * 32];
    const int tid  = threadIdx.x;
    const int lane = tid & 63;
    const int wave = tid >> 6;
    const int wr = wave >> 1, wc = wave & 1;
    const int m0 = blockIdx.y * 128, n0 = blockIdx.x * 128;
    const int r = lane & 15, quad = lane >> 4;

    f32x4 acc[4][4];
#pragma unroll
    for (int i = 0; i < 4; ++i)
#pragma unroll
        for (int j = 0; j < 4; ++j) acc[i][j] = (f32x4){0.f, 0.f, 0.f, 0.f};

    const int c0 = tid, c1 = tid + 256;
    const int row0 = c0 >> 2, kc0 = (c0 & 3) * 8;
    const int row1 = c1 >> 2, kc1 = (c1 & 3) * 8;
    const bf16* A0 = A + (size_t)(m0 + row0) * K + kc0;
    const bf16* A1 = A + (size_t)(m0 + row1) * K + kc1;
    const bf16* W0 = W + (size_t)(n0 + row0) * K + kc0;
    const bf16* W1p = W + (size_t)(n0 + row1) * K + kc1;

    for (int k0 = 0; k0 < K; k0 += 32) {
        gl_lds16(A0 + k0, As + c0 * 8);
        gl_lds16(A1 + k0, As + c1 * 8);
        gl_lds16(W0 + k0, Ws + c0 * 8);
        gl_lds16(W1p + k0, Ws + c1 * 8);
        __syncthreads();   // compiler emits vmcnt(0) drain before s_barrier

        bf16x8 a[4], b[4];
#pragma unroll
        for (int mt = 0; mt < 4; ++mt)
            a[mt] = *(const bf16x8*)(As + (wr * 64 + mt * 16 + r) * 32 + quad * 8);
#pragma unroll
        for (int nt = 0; nt < 4; ++nt)
            b[nt] = *(const bf16x8*)(Ws + (wc * 64 + nt * 16 + r) * 32 + quad * 8);
#pragma unroll
        for (int mt = 0; mt < 4; ++mt)
#pragma unroll
            for (int nt = 0; nt < 4; ++nt)
                acc[mt][nt] = __builtin_amdgcn_mfma_f32_16x16x32_bf16(a[mt], b[nt], acc[mt][nt], 0, 0, 0);
        __syncthreads();
    }

    // epilogue: D[row=quad*4+e][col=lane&15]
#pragma unroll
    for (int nt = 0; nt < 4; ++nt) {
        int n = n0 + wc * 64 + nt * 16 + r;
        float bv = bias[n];
#pragma unroll
        for (int mt = 0; mt < 4; ++mt) {
#pragma unroll
            for (int e = 0; e < 4; ++e) {
                int m = m0 + wr * 64 + mt * 16 + quad * 4 + e;
                float v = acc[mt][nt][e] + bv;
                if (ACT == 1) v = fmaxf(v, 0.f);
                C[(size_t)m * N + n] = (bf16)v;
            }
        }
    }
}

// ---------------- banded attention: one wave per (s, h), online softmax ----------------
// qkv layout: [S, 3*D]; q at h*64+d, k at 1024 + h*64+d, v at 2048 + h*64+d
__global__ __launch_bounds__(256)
void attn_kernel(const bf16* __restrict__ qkv, bf16* __restrict__ o)
{
    const int g = blockIdx.x * 4 + (threadIdx.x >> 6);
    const int lane = threadIdx.x & 63;
    const int s = g >> 4;
    const int h = g & 15;

    float q = (float)qkv[(size_t)s * 3072 + h * 64 + lane] * 0.125f;  // 1/sqrt(64)

    int j0 = s - (WINDOW - 1); if (j0 < 0) j0 = 0;
    int j1 = s + (WINDOW - 1); if (j1 > SEQ - 1) j1 = SEQ - 1;

    float m = -INFINITY, l = 0.f, acc = 0.f;
    for (int j = j0; j <= j1; ++j) {
        const bf16* kp = qkv + (size_t)j * 3072 + 1024 + h * 64;
        float prod = q * (float)kp[lane];
#pragma unroll
        for (int off = 32; off; off >>= 1) prod += __shfl_xor(prod, off, 64);
        float vn = (float)kp[1024 + lane];
        float mn = fmaxf(m, prod);
        float alpha = __expf(m - mn);      // first iter: exp(-inf)=0
        float p = __expf(prod - mn);
        l = l * alpha + p;
        acc = acc * alpha + p * vn;
        m = mn;
    }
    o[(size_t)s * 1024 + h * 64 + lane] = (bf16)(acc / l);
}

// ---------------- residual + layernorm (in-place on x), gamma/beta f32 ----------------
__global__ __launch_bounds__(256)
void ln_residual(bf16* __restrict__ x, const bf16* __restrict__ delta,
                 const float* __restrict__ gamma, const float* __restrict__ beta)
{
    const int s = blockIdx.x, tid = threadIdx.x;
    const int lane = tid & 63, wave = tid >> 6;
    __shared__ float red[8];
    float v[4];
    float sum = 0.f;
#pragma unroll
    for (int i = 0; i < 4; ++i) {
        int d = i * 256 + tid;
        v[i] = (float)x[(size_t)s * 1024 + d] + (float)delta[(size_t)s * 1024 + d];
        sum += v[i];
    }
#pragma unroll
    for (int off = 32; off; off >>= 1) sum += __shfl_xor(sum, off, 64);
    if (lane == 0) red[wave] = sum;
    __syncthreads();
    float mu = (red[0] + red[1] + red[2] + red[3]) * (1.f / 1024.f);
    float sq = 0.f;
#pragma unroll
    for (int i = 0; i < 4; ++i) { float t = v[i] - mu; sq += t * t; }
#pragma unroll
    for (int off = 32; off; off >>= 1) sq += __shfl_xor(sq, off, 64);
    if (lane == 0) red[wave + 4] = sq;
    __syncthreads();
    float var = (red[4] + red[5] + red[6] + red[7]) * (1.f / 1024.f);
    float inv = rsqrtf(var + LN_EPS);
#pragma unroll
    for (int i = 0; i < 4; ++i) {
        int d = i * 256 + tid;
        x[(size_t)s * 1024 + d] = (bf16)((v[i] - mu) * inv * gamma[d] + beta[d]);
    }
}

// ---------------- decoder: logits + log_softmax, one wave per row; f32 out ----------------
__global__ __launch_bounds__(256)
void decoder(const bf16* __restrict__ x, const float* __restrict__ Wdec,
             const float* __restrict__ bdec, float* __restrict__ out)
{
    const int s = blockIdx.x * 4 + (threadIdx.x >> 6);
    const int lane = threadIdx.x & 63;
    float a0 = 0.f, a1 = 0.f, a2 = 0.f;
    for (int d = lane; d < 1024; d += 64) {
        float xv = (float)x[(size_t)s * 1024 + d];
        a0 += xv * Wdec[d];
        a1 += xv * Wdec[1024 + d];
        a2 += xv * Wdec[2048 + d];
    }
#pragma unroll
    for (int off = 32; off; off >>= 1) {
        a0 += __shfl_xor(a0, off, 64);
        a1 += __shfl_xor(a1, off, 64);
        a2 += __shfl_xor(a2, off, 64);
    }
    if (lane == 0) {
        float z0 = a0 + bdec[0];
        float z1 = a1 + bdec[1];
        float z2 = a2 + bdec[2];
        float mx = fmaxf(z0, fmaxf(z1, z2));
        float lse = mx + logf(__expf(z0 - mx) + __expf(z1 - mx) + __expf(z2 - mx));
        out[s * 3 + 0] = z0 - lse;
        out[s * 3 + 1] = z1 - lse;
        out[s * 3 + 2] = z2 - lse;
    }
}

extern "C" void kernel_launch(void* const* d_in, const int* in_sizes, int n_in,
                              void* d_out, int out_size, void* d_ws, size_t ws_size,
                              hipStream_t stream)
{
    const float* X    = (const float*)d_in[0];
    const float* Wqkv = (const float*)d_in[1];
    const float* bqkv = (const float*)d_in[2];
    const float* Wo   = (const float*)d_in[3];
    const float* bo   = (const float*)d_in[4];
    const float* ln1g = (const float*)d_in[5];
    const float* ln1b = (const float*)d_in[6];
    const float* W1   = (const float*)d_in[7];
    const float* b1   = (const float*)d_in[8];
    const float* W2   = (const float*)d_in[9];
    const float* b2   = (const float*)d_in[10];
    const float* ln2g = (const float*)d_in[11];
    const float* ln2b = (const float*)d_in[12];
    const float* Wdec = (const float*)d_in[13];
    const float* bdec = (const float*)d_in[14];
    // d_in[15]=window_size(128), d_in[16]=nhead(16): compile-time constants

    // workspace layout (bf16 elements):
    //   x    [2M]
    //   buf  [8M]  : qkv = buf (6M), ao = buf+6M (2M); h = buf (8M, reuses qkv+ao after attention)
    //   tmp  [2M]
    //   wbuf [4.25M] : per-gemm bf16 weight staging (largest = 4096*1024)
    bf16* ws   = (bf16*)d_ws;
    bf16* x    = ws;                                  // 2,097,152
    bf16* buf  = x   + (size_t)SEQ * DMODEL;          // 8,388,608
    bf16* qkv  = buf;
    bf16* ao   = buf + (size_t)SEQ * 3 * DMODEL;
    bf16* h    = buf;
    bf16* tmp  = buf + (size_t)SEQ * DFF;             // 2,097,152
    bf16* wbuf = tmp + (size_t)SEQ * DMODEL;          // 4,194,304

    add_pe<<<(SEQ * DMODEL) / 256, 256, 0, stream>>>(X, x);

    for (int l = 0; l < 4; ++l) {
        // QKV projection
        cvt_bf16<<<(3072 * 1024 / 4 + 255) / 256, 256, 0, stream>>>(
            Wqkv + (size_t)l * 3072 * 1024, wbuf, 3072 * 1024 / 4);
        gemm_bt<0><<<dim3(3072 / 128, SEQ / 128), 256, 0, stream>>>(
            x, wbuf, bqkv + l * 3072, qkv, SEQ, 3072, 1024);
        // banded attention
        attn_kernel<<<(SEQ * NHEAD) / 4, 256, 0, stream>>>(qkv, ao);
        // O projection
        cvt_bf16<<<(1024 * 1024 / 4 + 255) / 256, 256, 0, stream>>>(
            Wo + (size_t)l * 1024 * 1024, wbuf, 1024 * 1024 / 4);
        gemm_bt<0><<<dim3(1024 / 128, SEQ / 128), 256, 0, stream>>>(
            ao, wbuf, bo + l * 1024, tmp, SEQ, 1024, 1024);
        ln_residual<<<SEQ, 256, 0, stream>>>(x, tmp, ln1g + l * 1024, ln1b + l * 1024);
        // FF1 (relu) — h overwrites qkv/ao region (dead now)
        cvt_bf16<<<(4096 * 1024 / 4 + 255) / 256, 256, 0, stream>>>(
            W1 + (size_t)l * 4096 * 1024, wbuf, 4096 * 1024 / 4);
        gemm_bt<1><<<dim3(4096 / 128, SEQ / 128), 256, 0, stream>>>(
            x, wbuf, b1 + l * 4096, h, SEQ, 4096, 1024);
        // FF2
        cvt_bf16<<<(1024 * 4096 / 4 + 255) / 256, 256, 0, stream>>>(
            W2 + (size_t)l * 1024 * 4096, wbuf, 1024 * 4096 / 4);
        gemm_bt<0><<<dim3(1024 / 128, SEQ / 128), 256, 0, stream>>>(
            h, wbuf, b2 + l * 1024, tmp, SEQ, 1024, 4096);
        ln_residual<<<SEQ, 256, 0, stream>>>(x, tmp, ln2g + l * 1024, ln2b + l * 1024);
    }

    decoder<<<SEQ / 4, 256, 0, stream>>>(x, Wdec, bdec, (float*)d_out);
}

// Round 4
// 1089.416 us; speedup vs baseline: 2.7954x; 2.7954x over previous
//
#include <hip/hip_runtime.h>
#include <hip/hip_bf16.h>
#include <cmath>

typedef __hip_bfloat16 bf16;
typedef __bf16 bf16x8 __attribute__((ext_vector_type(8)));
typedef __bf16 bf16x4 __attribute__((ext_vector_type(4)));
typedef float f32x4 __attribute__((ext_vector_type(4)));

typedef __attribute__((address_space(1))) void void_g;
typedef __attribute__((address_space(3))) void void_l;

#define SEQ 2048
#define DMODEL 1024
#define NHEAD 16
#define HDIM 64
#define DFF 4096
#define WINDOW 128
#define LN_EPS 1e-5f

__device__ __forceinline__ void gl_lds16(const bf16* g, bf16* l) {
    __builtin_amdgcn_global_load_lds((void_g*)(g), (void_l*)(l), 16, 0, 0);
}

// ---------------- f32 -> bf16 conversion (weights), 4 elems/thread ----------------
__global__ __launch_bounds__(256)
void cvt_bf16(const float* __restrict__ src, bf16* __restrict__ dst, int n4) {
    int i = blockIdx.x * 256 + threadIdx.x;
    if (i < n4) {
        float4 v = ((const float4*)src)[i];
        bf16x4 o;
        o[0] = (__bf16)v.x; o[1] = (__bf16)v.y; o[2] = (__bf16)v.z; o[3] = (__bf16)v.w;
        ((bf16x4*)dst)[i] = o;
    }
}

// ---------------- positional encoding add: f32 in -> bf16 out ----------------
__global__ __launch_bounds__(256)
void add_pe(const float* __restrict__ X, bf16* __restrict__ x) {
    int idx = blockIdx.x * 256 + threadIdx.x;     // over SEQ*DMODEL
    int s = idx >> 10, d = idx & 1023;
    float i2 = (float)(d & ~1);
    float div = expf(i2 * (-9.210340371976184f / 1024.0f));  // ln(10000)
    float ang = (float)s * div;
    float pe = (d & 1) ? cosf(ang) : sinf(ang);
    x[idx] = (bf16)(X[idx] + pe);
}

// ---------------- GEMM: C[M,N] = A[M,K] * W[N,K]^T + bias(f32), ACT=1 -> relu ----------------
template<int ACT>
__global__ __launch_bounds__(256)
void gemm_bt(const bf16* __restrict__ A, const bf16* __restrict__ W,
             const float* __restrict__ bias, bf16* __restrict__ C,
             int M, int N, int K)
{
    __shared__ __align__(16) bf16 As[128 * 32];
    __shared__ __align__(16) bf16 Ws[128 * 32];
    const int tid  = threadIdx.x;
    const int lane = tid & 63;
    const int wave = tid >> 6;
    const int wr = wave >> 1, wc = wave & 1;
    const int m0 = blockIdx.y * 128, n0 = blockIdx.x * 128;
    const int r = lane & 15, quad = lane >> 4;

    f32x4 acc[4][4];
#pragma unroll
    for (int i = 0; i < 4; ++i)
#pragma unroll
        for (int j = 0; j < 4; ++j) acc[i][j] = (f32x4){0.f, 0.f, 0.f, 0.f};

    const int c0 = tid, c1 = tid + 256;
    const int row0 = c0 >> 2, kc0 = (c0 & 3) * 8;
    const int row1 = c1 >> 2, kc1 = (c1 & 3) * 8;
    const bf16* A0 = A + (size_t)(m0 + row0) * K + kc0;
    const bf16* A1 = A + (size_t)(m0 + row1) * K + kc1;
    const bf16* W0 = W + (size_t)(n0 + row0) * K + kc0;
    const bf16* W1p = W + (size_t)(n0 + row1) * K + kc1;

    for (int k0 = 0; k0 < K; k0 += 32) {
        gl_lds16(A0 + k0, As + c0 * 8);
        gl_lds16(A1 + k0, As + c1 * 8);
        gl_lds16(W0 + k0, Ws + c0 * 8);
        gl_lds16(W1p + k0, Ws + c1 * 8);
        __syncthreads();

        bf16x8 a[4], b[4];
#pragma unroll
        for (int mt = 0; mt < 4; ++mt)
            a[mt] = *(const bf16x8*)(As + (wr * 64 + mt * 16 + r) * 32 + quad * 8);
#pragma unroll
        for (int nt = 0; nt < 4; ++nt)
            b[nt] = *(const bf16x8*)(Ws + (wc * 64 + nt * 16 + r) * 32 + quad * 8);
#pragma unroll
        for (int mt = 0; mt < 4; ++mt)
#pragma unroll
            for (int nt = 0; nt < 4; ++nt)
                acc[mt][nt] = __builtin_amdgcn_mfma_f32_16x16x32_bf16(a[mt], b[nt], acc[mt][nt], 0, 0, 0);
        __syncthreads();
    }

#pragma unroll
    for (int nt = 0; nt < 4; ++nt) {
        int n = n0 + wc * 64 + nt * 16 + r;
        float bv = bias[n];
#pragma unroll
        for (int mt = 0; mt < 4; ++mt) {
#pragma unroll
            for (int e = 0; e < 4; ++e) {
                int m = m0 + wr * 64 + mt * 16 + quad * 4 + e;
                float v = acc[mt][nt][e] + bv;
                if (ACT == 1) v = fmaxf(v, 0.f);
                C[(size_t)m * N + n] = (bf16)v;
            }
        }
    }
}

// ---------------- V transpose: qkv v-part [s][h*64+d] -> Vt[h*64+d][s] ----------------
__global__ __launch_bounds__(256)
void transpose_v(const bf16* __restrict__ qkv, bf16* __restrict__ Vt)
{
    __shared__ __bf16 t[64][66];
    const int s0 = blockIdx.x * 64, dm0 = blockIdx.y * 64;
    const int tid = threadIdx.x;
    const int sl = tid >> 2, dc = (tid & 3) * 16;
    const bf16* src = qkv + (size_t)(s0 + sl) * 3072 + 2048 + dm0 + dc;
    bf16x8 v0 = *(const bf16x8*)(src);
    bf16x8 v1 = *(const bf16x8*)(src + 8);
#pragma unroll
    for (int j = 0; j < 8; ++j) { t[sl][dc + j] = v0[j]; t[sl][dc + 8 + j] = v1[j]; }
    __syncthreads();
    const int dl = tid >> 2, sc = (tid & 3) * 16;
    bf16x8 o0, o1;
#pragma unroll
    for (int j = 0; j < 8; ++j) { o0[j] = t[sc + j][dl]; o1[j] = t[sc + 8 + j][dl]; }
    bf16* dst = Vt + (size_t)(dm0 + dl) * SEQ + s0 + sc;
    *(bf16x8*)(dst) = o0;
    *(bf16x8*)(dst + 8) = o1;
}

// ---------------- banded flash attention with MFMA ----------------
// block: 4 waves; head h = blockIdx.x & 15; wave w handles queries [qb*64+16w, +16)
__global__ __launch_bounds__(256)
void attn_mfma(const bf16* __restrict__ qkv, const bf16* __restrict__ Vt,
               bf16* __restrict__ o)
{
    __shared__ __align__(16) __bf16 Plds[4][16 * 40];  // per-wave P tile, pad 40 (80B rows)
    const int tid = threadIdx.x, lane = tid & 63, w = tid >> 6;
    const int h = blockIdx.x & 15;
    const int qw = (blockIdx.x >> 4) * 64 + w * 16;
    const int r = lane & 15, quad = lane >> 4;
    __bf16* P = Plds[w];

    // Q fragments, scaled by 1/sqrt(64)=0.125 (exact in bf16)
    bf16x8 qa[2];
    {
        const bf16* qrow = qkv + (size_t)(qw + r) * 3072 + h * 64 + quad * 8;
#pragma unroll
        for (int c = 0; c < 2; ++c) {
            bf16x8 t = *(const bf16x8*)(qrow + c * 32);
#pragma unroll
            for (int j = 0; j < 8; ++j) qa[c][j] = (__bf16)((float)t[j] * 0.125f);
        }
    }

    bf16x8 ones;
#pragma unroll
    for (int j = 0; j < 8; ++j) ones[j] = (__bf16)1.0f;

    f32x4 acc[4];
#pragma unroll
    for (int d = 0; d < 4; ++d) acc[d] = (f32x4){0.f, 0.f, 0.f, 0.f};
    float m_run[4], l_run[4];
#pragma unroll
    for (int e = 0; e < 4; ++e) { m_run[e] = -1e30f; l_run[e] = 0.f; }

    int jmin = qw - (WINDOW - 1); if (jmin < 0) jmin = 0;
    int jmax = qw + 15 + (WINDOW - 1); if (jmax > SEQ - 1) jmax = SEQ - 1;

    for (int kt = jmin & ~31; kt <= jmax; kt += 32) {
        // S = Q K^T for 16x32 tile (2 key chunks x 2 K-chain mfma)
        f32x4 S[2];
#pragma unroll
        for (int c = 0; c < 2; ++c) {
            const bf16* krow = qkv + (size_t)(kt + 16 * c + r) * 3072 + 1024 + h * 64 + quad * 8;
            bf16x8 kb0 = *(const bf16x8*)(krow);
            bf16x8 kb1 = *(const bf16x8*)(krow + 32);
            f32x4 s = (f32x4){0.f, 0.f, 0.f, 0.f};
            s = __builtin_amdgcn_mfma_f32_16x16x32_bf16(qa[0], kb0, s, 0, 0, 0);
            s = __builtin_amdgcn_mfma_f32_16x16x32_bf16(qa[1], kb1, s, 0, 0, 0);
            S[c] = s;
        }
        // band mask: valid iff |i-j| < 128   (C-layout: row=quad*4+e, col=16c+r)
#pragma unroll
        for (int c = 0; c < 2; ++c)
#pragma unroll
            for (int e = 0; e < 4; ++e) {
                int j = kt + 16 * c + r;
                int i = qw + quad * 4 + e;
                bool valid = (unsigned)(j - i + (WINDOW - 1)) <= (unsigned)(2 * WINDOW - 2);
                S[c][e] = valid ? S[c][e] : -1e30f;
            }
        // row max (across 16 lanes within quad group) + online-softmax update
        float alpha[4], mnew[4];
#pragma unroll
        for (int e = 0; e < 4; ++e) {
            float v = fmaxf(S[0][e], S[1][e]);
#pragma unroll
            for (int off = 1; off <= 8; off <<= 1) v = fmaxf(v, __shfl_xor(v, off, 64));
            mnew[e] = fmaxf(m_run[e], v);
            alpha[e] = __expf(m_run[e] - mnew[e]);
            m_run[e] = mnew[e];
        }
        // p = exp(s - m), zero masked, write to LDS (C-layout -> [row][key] tile)
#pragma unroll
        for (int c = 0; c < 2; ++c)
#pragma unroll
            for (int e = 0; e < 4; ++e) {
                float p = __expf(S[c][e] - mnew[e]);
                p = (S[c][e] <= -1e29f) ? 0.f : p;
                P[(quad * 4 + e) * 40 + 16 * c + r] = (__bf16)p;
            }
        // read P as A-fragment (wave-private LDS; compiler inserts lgkmcnt wait)
        bf16x8 pa = *(const bf16x8*)(P + r * 40 + quad * 8);
        // rescale accumulators and l
#pragma unroll
        for (int d = 0; d < 4; ++d)
#pragma unroll
            for (int e = 0; e < 4; ++e) acc[d][e] *= alpha[e];
        f32x4 ls = (f32x4){0.f, 0.f, 0.f, 0.f};
        ls = __builtin_amdgcn_mfma_f32_16x16x32_bf16(pa, ones, ls, 0, 0, 0);
#pragma unroll
        for (int e = 0; e < 4; ++e) l_run[e] = l_run[e] * alpha[e] + ls[e];
        // O += P V  (V^T rows contiguous in keys)
#pragma unroll
        for (int d = 0; d < 4; ++d) {
            const bf16* vrow = Vt + (size_t)(h * 64 + 16 * d + r) * SEQ + kt + quad * 8;
            bf16x8 vb = *(const bf16x8*)(vrow);
            acc[d] = __builtin_amdgcn_mfma_f32_16x16x32_bf16(pa, vb, acc[d], 0, 0, 0);
        }
    }

    // epilogue: o[row][h*64 + 16d + r] = acc/l
#pragma unroll
    for (int d = 0; d < 4; ++d)
#pragma unroll
        for (int e = 0; e < 4; ++e) {
            int i = qw + quad * 4 + e;
            o[(size_t)i * DMODEL + h * 64 + 16 * d + r] = (bf16)(acc[d][e] / l_run[e]);
        }
}

// ---------------- residual + layernorm (in-place on x), gamma/beta f32 ----------------
__global__ __launch_bounds__(256)
void ln_residual(bf16* __restrict__ x, const bf16* __restrict__ delta,
                 const float* __restrict__ gamma, const float* __restrict__ beta)
{
    const int s = blockIdx.x, tid = threadIdx.x;
    const int lane = tid & 63, wave = tid >> 6;
    __shared__ float red[8];
    float v[4];
    float sum = 0.f;
#pragma unroll
    for (int i = 0; i < 4; ++i) {
        int d = i * 256 + tid;
        v[i] = (float)x[(size_t)s * 1024 + d] + (float)delta[(size_t)s * 1024 + d];
        sum += v[i];
    }
#pragma unroll
    for (int off = 32; off; off >>= 1) sum += __shfl_xor(sum, off, 64);
    if (lane == 0) red[wave] = sum;
    __syncthreads();
    float mu = (red[0] + red[1] + red[2] + red[3]) * (1.f / 1024.f);
    float sq = 0.f;
#pragma unroll
    for (int i = 0; i < 4; ++i) { float t = v[i] - mu; sq += t * t; }
#pragma unroll
    for (int off = 32; off; off >>= 1) sq += __shfl_xor(sq, off, 64);
    if (lane == 0) red[wave + 4] = sq;
    __syncthreads();
    float var = (red[4] + red[5] + red[6] + red[7]) * (1.f / 1024.f);
    float inv = rsqrtf(var + LN_EPS);
#pragma unroll
    for (int i = 0; i < 4; ++i) {
        int d = i * 256 + tid;
        x[(size_t)s * 1024 + d] = (bf16)((v[i] - mu) * inv * gamma[d] + beta[d]);
    }
}

// ---------------- decoder: logits + log_softmax, one wave per row; f32 out ----------------
__global__ __launch_bounds__(256)
void decoder(const bf16* __restrict__ x, const float* __restrict__ Wdec,
             const float* __restrict__ bdec, float* __restrict__ out)
{
    const int s = blockIdx.x * 4 + (threadIdx.x >> 6);
    const int lane = threadIdx.x & 63;
    float a0 = 0.f, a1 = 0.f, a2 = 0.f;
    for (int d = lane; d < 1024; d += 64) {
        float xv = (float)x[(size_t)s * 1024 + d];
        a0 += xv * Wdec[d];
        a1 += xv * Wdec[1024 + d];
        a2 += xv * Wdec[2048 + d];
    }
#pragma unroll
    for (int off = 32; off; off >>= 1) {
        a0 += __shfl_xor(a0, off, 64);
        a1 += __shfl_xor(a1, off, 64);
        a2 += __shfl_xor(a2, off, 64);
    }
    if (lane == 0) {
        float z0 = a0 + bdec[0];
        float z1 = a1 + bdec[1];
        float z2 = a2 + bdec[2];
        float mx = fmaxf(z0, fmaxf(z1, z2));
        float lse = mx + logf(__expf(z0 - mx) + __expf(z1 - mx) + __expf(z2 - mx));
        out[s * 3 + 0] = z0 - lse;
        out[s * 3 + 1] = z1 - lse;
        out[s * 3 + 2] = z2 - lse;
    }
}

extern "C" void kernel_launch(void* const* d_in, const int* in_sizes, int n_in,
                              void* d_out, int out_size, void* d_ws, size_t ws_size,
                              hipStream_t stream)
{
    const float* X    = (const float*)d_in[0];
    const float* Wqkv = (const float*)d_in[1];
    const float* bqkv = (const float*)d_in[2];
    const float* Wo   = (const float*)d_in[3];
    const float* bo   = (const float*)d_in[4];
    const float* ln1g = (const float*)d_in[5];
    const float* ln1b = (const float*)d_in[6];
    const float* W1   = (const float*)d_in[7];
    const float* b1   = (const float*)d_in[8];
    const float* W2   = (const float*)d_in[9];
    const float* b2   = (const float*)d_in[10];
    const float* ln2g = (const float*)d_in[11];
    const float* ln2b = (const float*)d_in[12];
    const float* Wdec = (const float*)d_in[13];
    const float* bdec = (const float*)d_in[14];

    // workspace layout (bf16 elements):
    //   x    [2M] ; buf [8M] (qkv 6M | ao 2M; reused as h 8M) ; tmp [2M] (also Vt during attn)
    //   wbuf [4M] per-gemm bf16 weight staging
    bf16* ws   = (bf16*)d_ws;
    bf16* x    = ws;                                  // 2,097,152
    bf16* buf  = x   + (size_t)SEQ * DMODEL;          // 8,388,608
    bf16* qkv  = buf;
    bf16* ao   = buf + (size_t)SEQ * 3 * DMODEL;
    bf16* h    = buf;
    bf16* tmp  = buf + (size_t)SEQ * DFF;             // 2,097,152 (Vt alias)
    bf16* Vt   = tmp;
    bf16* wbuf = tmp + (size_t)SEQ * DMODEL;          // 4,194,304

    add_pe<<<(SEQ * DMODEL) / 256, 256, 0, stream>>>(X, x);

    for (int l = 0; l < 4; ++l) {
        // QKV projection
        cvt_bf16<<<(3072 * 1024 / 4 + 255) / 256, 256, 0, stream>>>(
            Wqkv + (size_t)l * 3072 * 1024, wbuf, 3072 * 1024 / 4);
        gemm_bt<0><<<dim3(3072 / 128, SEQ / 128), 256, 0, stream>>>(
            x, wbuf, bqkv + l * 3072, qkv, SEQ, 3072, 1024);
        // banded flash attention (Vt staged in tmp, dead until O-proj)
        transpose_v<<<dim3(SEQ / 64, DMODEL / 64), 256, 0, stream>>>(qkv, Vt);
        attn_mfma<<<(SEQ / 64) * NHEAD, 256, 0, stream>>>(qkv, Vt, ao);
        // O projection
        cvt_bf16<<<(1024 * 1024 / 4 + 255) / 256, 256, 0, stream>>>(
            Wo + (size_t)l * 1024 * 1024, wbuf, 1024 * 1024 / 4);
        gemm_bt<0><<<dim3(1024 / 128, SEQ / 128), 256, 0, stream>>>(
            ao, wbuf, bo + l * 1024, tmp, SEQ, 1024, 1024);
        ln_residual<<<SEQ, 256, 0, stream>>>(x, tmp, ln1g + l * 1024, ln1b + l * 1024);
        // FF1 (relu) — h overwrites qkv/ao region (dead now)
        cvt_bf16<<<(4096 * 1024 / 4 + 255) / 256, 256, 0, stream>>>(
            W1 + (size_t)l * 4096 * 1024, wbuf, 4096 * 1024 / 4);
        gemm_bt<1><<<dim3(4096 / 128, SEQ / 128), 256, 0, stream>>>(
            x, wbuf, b1 + l * 4096, h, SEQ, 4096, 1024);
        // FF2
        cvt_bf16<<<(1024 * 4096 / 4 + 255) / 256, 256, 0, stream>>>(
            W2 + (size_t)l * 1024 * 4096, wbuf, 1024 * 4096 / 4);
        gemm_bt<0><<<dim3(1024 / 128, SEQ / 128), 256, 0, stream>>>(
            h, wbuf, b2 + l * 1024, tmp, SEQ, 1024, 4096);
        ln_residual<<<SEQ, 256, 0, stream>>>(x, tmp, ln2g + l * 1024, ln2b + l * 1024);
    }

    decoder<<<SEQ / 4, 256, 0, stream>>>(x, Wdec, bdec, (float*)d_out);
}

// Round 5
// 999.684 us; speedup vs baseline: 3.0463x; 1.0898x over previous
//
#include <hip/hip_runtime.h>
#include <hip/hip_bf16.h>
#include <cmath>

typedef __hip_bfloat16 bf16;
typedef __bf16 bf16x8 __attribute__((ext_vector_type(8)));
typedef __bf16 bf16x4 __attribute__((ext_vector_type(4)));
typedef float f32x4 __attribute__((ext_vector_type(4)));

typedef __attribute__((address_space(1))) void void_g;
typedef __attribute__((address_space(3))) void void_l;

#define SEQ 2048
#define DMODEL 1024
#define NHEAD 16
#define HDIM 64
#define DFF 4096
#define WINDOW 128
#define LN_EPS 1e-5f

__device__ __forceinline__ void gl_lds16(const bf16* g, bf16* l) {
    __builtin_amdgcn_global_load_lds((void_g*)(g), (void_l*)(l), 16, 0, 0);
}

// ---------------- f32 -> bf16 conversion (weights), 4 elems/thread ----------------
__global__ __launch_bounds__(256)
void cvt_bf16(const float* __restrict__ src, bf16* __restrict__ dst, int n4) {
    int i = blockIdx.x * 256 + threadIdx.x;
    if (i < n4) {
        float4 v = ((const float4*)src)[i];
        bf16x4 o;
        o[0] = (__bf16)v.x; o[1] = (__bf16)v.y; o[2] = (__bf16)v.z; o[3] = (__bf16)v.w;
        ((bf16x4*)dst)[i] = o;
    }
}

// ---------------- zero f32 buffer (avoid hipMemsetAsync API in capture) ----------------
__global__ __launch_bounds__(256)
void zero_f32(float4* __restrict__ p) {
    p[blockIdx.x * 256 + threadIdx.x] = (float4){0.f, 0.f, 0.f, 0.f};
}

// ---------------- positional encoding add: f32 in -> bf16 out ----------------
__global__ __launch_bounds__(256)
void add_pe(const float* __restrict__ X, bf16* __restrict__ x) {
    int idx = blockIdx.x * 256 + threadIdx.x;     // over SEQ*DMODEL
    int s = idx >> 10, d = idx & 1023;
    float i2 = (float)(d & ~1);
    float div = expf(i2 * (-9.210340371976184f / 1024.0f));  // ln(10000)
    float ang = (float)s * div;
    float pe = (d & 1) ? cosf(ang) : sinf(ang);
    x[idx] = (bf16)(X[idx] + pe);
}

// ======================= GEMM core (XOR-swizzled LDS) =======================
// LDS tile 128x32; chunk c (16B) holds row=c>>2, k-chunk ((c&3)^(row&3)).
// Fragment read: row = base+r -> row&3 == r&3, col chunk = quad^(r&3) (const/thread).

// ---------------- direct GEMM: C[M,N] = A[M,K] * W[N,K]^T + bias(f32) ----------------
template<int ACT>
__global__ __launch_bounds__(256)
void gemm_bt(const bf16* __restrict__ A, const bf16* __restrict__ W,
             const float* __restrict__ bias, bf16* __restrict__ C,
             int M, int N, int K)
{
    __shared__ __align__(16) bf16 As[128 * 32];
    __shared__ __align__(16) bf16 Ws[128 * 32];
    const int tid  = threadIdx.x;
    const int lane = tid & 63;
    const int wave = tid >> 6;
    const int wr = wave >> 1, wc = wave & 1;
    const int m0 = blockIdx.y * 128, n0 = blockIdx.x * 128;
    const int r = lane & 15, quad = lane >> 4;
    const int rc = (quad ^ (r & 3)) * 8;          // swizzled read k-chunk offset

    f32x4 acc[4][4];
#pragma unroll
    for (int i = 0; i < 4; ++i)
#pragma unroll
        for (int j = 0; j < 4; ++j) acc[i][j] = (f32x4){0.f, 0.f, 0.f, 0.f};

    const int c0 = tid, c1 = tid + 256;
    const int row0 = c0 >> 2, kc0 = (((c0 & 3) ^ (row0 & 3)) * 8);
    const int row1 = c1 >> 2, kc1 = (((c1 & 3) ^ (row1 & 3)) * 8);
    const bf16* A0 = A + (size_t)(m0 + row0) * K + kc0;
    const bf16* A1 = A + (size_t)(m0 + row1) * K + kc1;
    const bf16* W0 = W + (size_t)(n0 + row0) * K + kc0;
    const bf16* W1p = W + (size_t)(n0 + row1) * K + kc1;

    for (int k0 = 0; k0 < K; k0 += 32) {
        gl_lds16(A0 + k0, As + c0 * 8);
        gl_lds16(A1 + k0, As + c1 * 8);
        gl_lds16(W0 + k0, Ws + c0 * 8);
        gl_lds16(W1p + k0, Ws + c1 * 8);
        __syncthreads();

        bf16x8 a[4], b[4];
#pragma unroll
        for (int mt = 0; mt < 4; ++mt)
            a[mt] = *(const bf16x8*)(As + (wr * 64 + mt * 16 + r) * 32 + rc);
#pragma unroll
        for (int nt = 0; nt < 4; ++nt)
            b[nt] = *(const bf16x8*)(Ws + (wc * 64 + nt * 16 + r) * 32 + rc);
#pragma unroll
        for (int mt = 0; mt < 4; ++mt)
#pragma unroll
            for (int nt = 0; nt < 4; ++nt)
                acc[mt][nt] = __builtin_amdgcn_mfma_f32_16x16x32_bf16(a[mt], b[nt], acc[mt][nt], 0, 0, 0);
        __syncthreads();
    }

#pragma unroll
    for (int nt = 0; nt < 4; ++nt) {
        int n = n0 + wc * 64 + nt * 16 + r;
        float bv = bias[n];
#pragma unroll
        for (int mt = 0; mt < 4; ++mt) {
#pragma unroll
            for (int e = 0; e < 4; ++e) {
                int m = m0 + wr * 64 + mt * 16 + quad * 4 + e;
                float v = acc[mt][nt][e] + bv;
                if (ACT == 1) v = fmaxf(v, 0.f);
                C[(size_t)m * N + n] = (bf16)v;
            }
        }
    }
}

// ---------------- split-K GEMM: Cacc[M,N] += A * W^T (f32 atomic), no bias ----------------
template<int SPLIT>
__global__ __launch_bounds__(256)
void gemm_bt_splitk(const bf16* __restrict__ A, const bf16* __restrict__ W,
                    float* __restrict__ Cacc, int M, int N, int K)
{
    __shared__ __align__(16) bf16 As[128 * 32];
    __shared__ __align__(16) bf16 Ws[128 * 32];
    const int tid  = threadIdx.x;
    const int lane = tid & 63;
    const int wave = tid >> 6;
    const int wr = wave >> 1, wc = wave & 1;
    const int m0 = blockIdx.y * 128, n0 = blockIdx.x * 128;
    const int Kc = K / SPLIT;
    const int kbase = blockIdx.z * Kc;
    const int r = lane & 15, quad = lane >> 4;
    const int rc = (quad ^ (r & 3)) * 8;

    f32x4 acc[4][4];
#pragma unroll
    for (int i = 0; i < 4; ++i)
#pragma unroll
        for (int j = 0; j < 4; ++j) acc[i][j] = (f32x4){0.f, 0.f, 0.f, 0.f};

    const int c0 = tid, c1 = tid + 256;
    const int row0 = c0 >> 2, kc0 = (((c0 & 3) ^ (row0 & 3)) * 8);
    const int row1 = c1 >> 2, kc1 = (((c1 & 3) ^ (row1 & 3)) * 8);
    const bf16* A0 = A + (size_t)(m0 + row0) * K + kbase + kc0;
    const bf16* A1 = A + (size_t)(m0 + row1) * K + kbase + kc1;
    const bf16* W0 = W + (size_t)(n0 + row0) * K + kbase + kc0;
    const bf16* W1p = W + (size_t)(n0 + row1) * K + kbase + kc1;

    for (int k0 = 0; k0 < Kc; k0 += 32) {
        gl_lds16(A0 + k0, As + c0 * 8);
        gl_lds16(A1 + k0, As + c1 * 8);
        gl_lds16(W0 + k0, Ws + c0 * 8);
        gl_lds16(W1p + k0, Ws + c1 * 8);
        __syncthreads();

        bf16x8 a[4], b[4];
#pragma unroll
        for (int mt = 0; mt < 4; ++mt)
            a[mt] = *(const bf16x8*)(As + (wr * 64 + mt * 16 + r) * 32 + rc);
#pragma unroll
        for (int nt = 0; nt < 4; ++nt)
            b[nt] = *(const bf16x8*)(Ws + (wc * 64 + nt * 16 + r) * 32 + rc);
#pragma unroll
        for (int mt = 0; mt < 4; ++mt)
#pragma unroll
            for (int nt = 0; nt < 4; ++nt)
                acc[mt][nt] = __builtin_amdgcn_mfma_f32_16x16x32_bf16(a[mt], b[nt], acc[mt][nt], 0, 0, 0);
        __syncthreads();
    }

#pragma unroll
    for (int nt = 0; nt < 4; ++nt) {
        int n = n0 + wc * 64 + nt * 16 + r;
#pragma unroll
        for (int mt = 0; mt < 4; ++mt) {
#pragma unroll
            for (int e = 0; e < 4; ++e) {
                int m = m0 + wr * 64 + mt * 16 + quad * 4 + e;
                atomicAdd(&Cacc[(size_t)m * N + n], acc[mt][nt][e]);
            }
        }
    }
}

// ---------------- V transpose: qkv v-part [s][h*64+d] -> Vt[h*64+d][s] ----------------
__global__ __launch_bounds__(256)
void transpose_v(const bf16* __restrict__ qkv, bf16* __restrict__ Vt)
{
    __shared__ __bf16 t[64][66];
    const int s0 = blockIdx.x * 64, dm0 = blockIdx.y * 64;
    const int tid = threadIdx.x;
    const int sl = tid >> 2, dc = (tid & 3) * 16;
    const bf16* src = qkv + (size_t)(s0 + sl) * 3072 + 2048 + dm0 + dc;
    bf16x8 v0 = *(const bf16x8*)(src);
    bf16x8 v1 = *(const bf16x8*)(src + 8);
#pragma unroll
    for (int j = 0; j < 8; ++j) { t[sl][dc + j] = v0[j]; t[sl][dc + 8 + j] = v1[j]; }
    __syncthreads();
    const int dl = tid >> 2, sc = (tid & 3) * 16;
    bf16x8 o0, o1;
#pragma unroll
    for (int j = 0; j < 8; ++j) { o0[j] = t[sc + j][dl]; o1[j] = t[sc + 8 + j][dl]; }
    bf16* dst = Vt + (size_t)(dm0 + dl) * SEQ + s0 + sc;
    *(bf16x8*)(dst) = o0;
    *(bf16x8*)(dst + 8) = o1;
}

// ---------------- banded flash attention with MFMA ----------------
__global__ __launch_bounds__(256)
void attn_mfma(const bf16* __restrict__ qkv, const bf16* __restrict__ Vt,
               bf16* __restrict__ o)
{
    __shared__ __align__(16) __bf16 Plds[4][16 * 40];  // per-wave P tile, pad 40 (80B rows)
    const int tid = threadIdx.x, lane = tid & 63, w = tid >> 6;
    const int h = blockIdx.x & 15;
    const int qw = (blockIdx.x >> 4) * 64 + w * 16;
    const int r = lane & 15, quad = lane >> 4;
    __bf16* P = Plds[w];

    bf16x8 qa[2];
    {
        const bf16* qrow = qkv + (size_t)(qw + r) * 3072 + h * 64 + quad * 8;
#pragma unroll
        for (int c = 0; c < 2; ++c) {
            bf16x8 t = *(const bf16x8*)(qrow + c * 32);
#pragma unroll
            for (int j = 0; j < 8; ++j) qa[c][j] = (__bf16)((float)t[j] * 0.125f);
        }
    }

    bf16x8 ones;
#pragma unroll
    for (int j = 0; j < 8; ++j) ones[j] = (__bf16)1.0f;

    f32x4 acc[4];
#pragma unroll
    for (int d = 0; d < 4; ++d) acc[d] = (f32x4){0.f, 0.f, 0.f, 0.f};
    float m_run[4], l_run[4];
#pragma unroll
    for (int e = 0; e < 4; ++e) { m_run[e] = -1e30f; l_run[e] = 0.f; }

    int jmin = qw - (WINDOW - 1); if (jmin < 0) jmin = 0;
    int jmax = qw + 15 + (WINDOW - 1); if (jmax > SEQ - 1) jmax = SEQ - 1;

    for (int kt = jmin & ~31; kt <= jmax; kt += 32) {
        f32x4 S[2];
#pragma unroll
        for (int c = 0; c < 2; ++c) {
            const bf16* krow = qkv + (size_t)(kt + 16 * c + r) * 3072 + 1024 + h * 64 + quad * 8;
            bf16x8 kb0 = *(const bf16x8*)(krow);
            bf16x8 kb1 = *(const bf16x8*)(krow + 32);
            f32x4 s = (f32x4){0.f, 0.f, 0.f, 0.f};
            s = __builtin_amdgcn_mfma_f32_16x16x32_bf16(qa[0], kb0, s, 0, 0, 0);
            s = __builtin_amdgcn_mfma_f32_16x16x32_bf16(qa[1], kb1, s, 0, 0, 0);
            S[c] = s;
        }
#pragma unroll
        for (int c = 0; c < 2; ++c)
#pragma unroll
            for (int e = 0; e < 4; ++e) {
                int j = kt + 16 * c + r;
                int i = qw + quad * 4 + e;
                bool valid = (unsigned)(j - i + (WINDOW - 1)) <= (unsigned)(2 * WINDOW - 2);
                S[c][e] = valid ? S[c][e] : -1e30f;
            }
        float alpha[4], mnew[4];
#pragma unroll
        for (int e = 0; e < 4; ++e) {
            float v = fmaxf(S[0][e], S[1][e]);
#pragma unroll
            for (int off = 1; off <= 8; off <<= 1) v = fmaxf(v, __shfl_xor(v, off, 64));
            mnew[e] = fmaxf(m_run[e], v);
            alpha[e] = __expf(m_run[e] - mnew[e]);
            m_run[e] = mnew[e];
        }
#pragma unroll
        for (int c = 0; c < 2; ++c)
#pragma unroll
            for (int e = 0; e < 4; ++e) {
                float p = __expf(S[c][e] - mnew[e]);
                p = (S[c][e] <= -1e29f) ? 0.f : p;
                P[(quad * 4 + e) * 40 + 16 * c + r] = (__bf16)p;
            }
        bf16x8 pa = *(const bf16x8*)(P + r * 40 + quad * 8);
#pragma unroll
        for (int d = 0; d < 4; ++d)
#pragma unroll
            for (int e = 0; e < 4; ++e) acc[d][e] *= alpha[e];
        f32x4 ls = (f32x4){0.f, 0.f, 0.f, 0.f};
        ls = __builtin_amdgcn_mfma_f32_16x16x32_bf16(pa, ones, ls, 0, 0, 0);
#pragma unroll
        for (int e = 0; e < 4; ++e) l_run[e] = l_run[e] * alpha[e] + ls[e];
#pragma unroll
        for (int d = 0; d < 4; ++d) {
            const bf16* vrow = Vt + (size_t)(h * 64 + 16 * d + r) * SEQ + kt + quad * 8;
            bf16x8 vb = *(const bf16x8*)(vrow);
            acc[d] = __builtin_amdgcn_mfma_f32_16x16x32_bf16(pa, vb, acc[d], 0, 0, 0);
        }
    }

#pragma unroll
    for (int d = 0; d < 4; ++d)
#pragma unroll
        for (int e = 0; e < 4; ++e) {
            int i = qw + quad * 4 + e;
            o[(size_t)i * DMODEL + h * 64 + 16 * d + r] = (bf16)(acc[d][e] / l_run[e]);
        }
}

// ---------------- residual + layernorm, delta = f32 acc + f32 bias; in-place on x ----------------
__global__ __launch_bounds__(256)
void ln_residual_f32(bf16* __restrict__ x, const float* __restrict__ accd,
                     const float* __restrict__ bias,
                     const float* __restrict__ gamma, const float* __restrict__ beta)
{
    const int s = blockIdx.x, tid = threadIdx.x;
    const int lane = tid & 63, wave = tid >> 6;
    __shared__ float red[8];
    float v[4];
    float sum = 0.f;
#pragma unroll
    for (int i = 0; i < 4; ++i) {
        int d = i * 256 + tid;
        v[i] = (float)x[(size_t)s * 1024 + d] + accd[(size_t)s * 1024 + d] + bias[d];
        sum += v[i];
    }
#pragma unroll
    for (int off = 32; off; off >>= 1) sum += __shfl_xor(sum, off, 64);
    if (lane == 0) red[wave] = sum;
    __syncthreads();
    float mu = (red[0] + red[1] + red[2] + red[3]) * (1.f / 1024.f);
    float sq = 0.f;
#pragma unroll
    for (int i = 0; i < 4; ++i) { float t = v[i] - mu; sq += t * t; }
#pragma unroll
    for (int off = 32; off; off >>= 1) sq += __shfl_xor(sq, off, 64);
    if (lane == 0) red[wave + 4] = sq;
    __syncthreads();
    float var = (red[4] + red[5] + red[6] + red[7]) * (1.f / 1024.f);
    float inv = rsqrtf(var + LN_EPS);
#pragma unroll
    for (int i = 0; i < 4; ++i) {
        int d = i * 256 + tid;
        x[(size_t)s * 1024 + d] = (bf16)((v[i] - mu) * inv * gamma[d] + beta[d]);
    }
}

// ---------------- decoder: logits + log_softmax, one wave per row; f32 out ----------------
__global__ __launch_bounds__(256)
void decoder(const bf16* __restrict__ x, const float* __restrict__ Wdec,
             const float* __restrict__ bdec, float* __restrict__ out)
{
    const int s = blockIdx.x * 4 + (threadIdx.x >> 6);
    const int lane = threadIdx.x & 63;
    float a0 = 0.f, a1 = 0.f, a2 = 0.f;
    for (int d = lane; d < 1024; d += 64) {
        float xv = (float)x[(size_t)s * 1024 + d];
        a0 += xv * Wdec[d];
        a1 += xv * Wdec[1024 + d];
        a2 += xv * Wdec[2048 + d];
    }
#pragma unroll
    for (int off = 32; off; off >>= 1) {
        a0 += __shfl_xor(a0, off, 64);
        a1 += __shfl_xor(a1, off, 64);
        a2 += __shfl_xor(a2, off, 64);
    }
    if (lane == 0) {
        float z0 = a0 + bdec[0];
        float z1 = a1 + bdec[1];
        float z2 = a2 + bdec[2];
        float mx = fmaxf(z0, fmaxf(z1, z2));
        float lse = mx + logf(__expf(z0 - mx) + __expf(z1 - mx) + __expf(z2 - mx));
        out[s * 3 + 0] = z0 - lse;
        out[s * 3 + 1] = z1 - lse;
        out[s * 3 + 2] = z2 - lse;
    }
}

extern "C" void kernel_launch(void* const* d_in, const int* in_sizes, int n_in,
                              void* d_out, int out_size, void* d_ws, size_t ws_size,
                              hipStream_t stream)
{
    const float* X    = (const float*)d_in[0];
    const float* Wqkv = (const float*)d_in[1];
    const float* bqkv = (const float*)d_in[2];
    const float* Wo   = (const float*)d_in[3];
    const float* bo   = (const float*)d_in[4];
    const float* ln1g = (const float*)d_in[5];
    const float* ln1b = (const float*)d_in[6];
    const float* W1   = (const float*)d_in[7];
    const float* b1   = (const float*)d_in[8];
    const float* W2   = (const float*)d_in[9];
    const float* b2   = (const float*)d_in[10];
    const float* ln2g = (const float*)d_in[11];
    const float* ln2b = (const float*)d_in[12];
    const float* Wdec = (const float*)d_in[13];
    const float* bdec = (const float*)d_in[14];

    // workspace (bf16 elems): x[2M] | buf[8M]=qkv6M/ao2M (reused as h) | tmp[2M]=Vt
    //                         wbuf[4M] weight staging | accf: 2M f32 split-K accumulator
    bf16* ws   = (bf16*)d_ws;
    bf16* x    = ws;                                  // 2M
    bf16* buf  = x   + (size_t)SEQ * DMODEL;          // 8M
    bf16* qkv  = buf;
    bf16* ao   = buf + (size_t)SEQ * 3 * DMODEL;
    bf16* h    = buf;
    bf16* tmp  = buf + (size_t)SEQ * DFF;             // 2M (Vt)
    bf16* Vt   = tmp;
    bf16* wbuf = tmp + (size_t)SEQ * DMODEL;          // 4M
    float* accf = (float*)(wbuf + (size_t)DFF * DMODEL);  // 2M f32 (8 MB)

    add_pe<<<(SEQ * DMODEL) / 256, 256, 0, stream>>>(X, x);

    for (int l = 0; l < 4; ++l) {
        // QKV projection (direct)
        cvt_bf16<<<(3072 * 1024 / 4) / 256, 256, 0, stream>>>(
            Wqkv + (size_t)l * 3072 * 1024, wbuf, 3072 * 1024 / 4);
        gemm_bt<0><<<dim3(3072 / 128, SEQ / 128), 256, 0, stream>>>(
            x, wbuf, bqkv + l * 3072, qkv, SEQ, 3072, 1024);
        // banded flash attention
        transpose_v<<<dim3(SEQ / 64, DMODEL / 64), 256, 0, stream>>>(qkv, Vt);
        attn_mfma<<<(SEQ / 64) * NHEAD, 256, 0, stream>>>(qkv, Vt, ao);
        // O projection (split-K=4, f32 atomic; bias folded into LN)
        cvt_bf16<<<(1024 * 1024 / 4) / 256, 256, 0, stream>>>(
            Wo + (size_t)l * 1024 * 1024, wbuf, 1024 * 1024 / 4);
        zero_f32<<<(SEQ * DMODEL / 4) / 256, 256, 0, stream>>>((float4*)accf);
        gemm_bt_splitk<4><<<dim3(1024 / 128, SEQ / 128, 4), 256, 0, stream>>>(
            ao, wbuf, accf, SEQ, 1024, 1024);
        ln_residual_f32<<<SEQ, 256, 0, stream>>>(x, accf, bo + l * 1024,
                                                 ln1g + l * 1024, ln1b + l * 1024);
        // FF1 (relu, direct) — h overwrites qkv/ao region
        cvt_bf16<<<(4096 * 1024 / 4) / 256, 256, 0, stream>>>(
            W1 + (size_t)l * 4096 * 1024, wbuf, 4096 * 1024 / 4);
        gemm_bt<1><<<dim3(4096 / 128, SEQ / 128), 256, 0, stream>>>(
            x, wbuf, b1 + l * 4096, h, SEQ, 4096, 1024);
        // FF2 (split-K=4, f32 atomic; bias folded into LN)
        cvt_bf16<<<(1024 * 4096 / 4) / 256, 256, 0, stream>>>(
            W2 + (size_t)l * 1024 * 4096, wbuf, 1024 * 4096 / 4);
        zero_f32<<<(SEQ * DMODEL / 4) / 256, 256, 0, stream>>>((float4*)accf);
        gemm_bt_splitk<4><<<dim3(1024 / 128, SEQ / 128, 4), 256, 0, stream>>>(
            h, wbuf, accf, SEQ, 1024, 4096);
        ln_residual_f32<<<SEQ, 256, 0, stream>>>(x, accf, b2 + l * 1024,
                                                 ln2g + l * 1024, ln2b + l * 1024);
    }

    decoder<<<SEQ / 4, 256, 0, stream>>>(x, Wdec, bdec, (float*)d_out);
}

// Round 6
// 921.333 us; speedup vs baseline: 3.3054x; 1.0850x over previous
//
#include <hip/hip_runtime.h>
#include <hip/hip_bf16.h>
#include <cmath>

typedef __hip_bfloat16 bf16;
typedef __bf16 bf16x8 __attribute__((ext_vector_type(8)));
typedef float f32x4 __attribute__((ext_vector_type(4)));

typedef __attribute__((address_space(1))) void void_g;
typedef __attribute__((address_space(3))) void void_l;

#define SEQ 2048
#define DMODEL 1024
#define NHEAD 16
#define HDIM 64
#define DFF 4096
#define WINDOW 128
#define LN_EPS 1e-5f

__device__ __forceinline__ void gl_lds16(const bf16* g, bf16* l) {
    __builtin_amdgcn_global_load_lds((void_g*)(g), (void_l*)(l), 16, 0, 0);
}

// ---------------- zero f32 buffer ----------------
__global__ __launch_bounds__(256)
void zero_f32(float4* __restrict__ p) {
    p[blockIdx.x * 256 + threadIdx.x] = (float4){0.f, 0.f, 0.f, 0.f};
}

// ---------------- positional encoding add: f32 in -> bf16 out ----------------
__global__ __launch_bounds__(256)
void add_pe(const float* __restrict__ X, bf16* __restrict__ x) {
    int idx = blockIdx.x * 256 + threadIdx.x;
    int s = idx >> 10, d = idx & 1023;
    float i2 = (float)(d & ~1);
    float div = expf(i2 * (-9.210340371976184f / 1024.0f));
    float ang = (float)s * div;
    float pe = (d & 1) ? cosf(ang) : sinf(ang);
    x[idx] = (bf16)(X[idx] + pe);
}

// ======================= GEMM core, BK=64 =======================
// LDS: two ks-major halves of 128x32 bf16 each (proven BK=32 layout per half).
// A: async global_load_lds (LDS linear, source-address swizzled).
// W: f32 source, VGPR-staged (float4 x2 -> cvt -> ds_write_b128), prefetched
//    during the compute phase of the previous iteration.
// chunk c in [0,1024): ks=c>>9, row=(c>>2)&127, kch=(c&3)^(row&3)
// frag read (half ks): elems ks*4096 + row*32 + (quad^(r&3))*8

#define GEMM_PROLOGUE(Adecl, Wdecl)                                              \
    __shared__ __align__(16) bf16 As[2 * 128 * 32];                              \
    __shared__ __align__(16) bf16 Ws[2 * 128 * 32];                              \
    const int tid  = threadIdx.x;                                                \
    const int lane = tid & 63;                                                   \
    const int wave = tid >> 6;                                                   \
    const int wr = wave >> 1, wc = wave & 1;                                     \
    const int r = lane & 15, quad = lane >> 4;                                   \
    const int rc = (quad ^ (r & 3)) * 8;                                         \
    f32x4 acc[4][4];                                                             \
    _Pragma("unroll")                                                            \
    for (int i = 0; i < 4; ++i)                                                  \
        _Pragma("unroll")                                                        \
        for (int j = 0; j < 4; ++j) acc[i][j] = (f32x4){0.f, 0.f, 0.f, 0.f};     \
    const bf16* Ap[4]; const float* Wp[4];                                       \
    _Pragma("unroll")                                                            \
    for (int i = 0; i < 4; ++i) {                                                \
        int c = tid + 256 * i;                                                   \
        int ks = c >> 9, row = (c >> 2) & 127, kch = (c & 3) ^ (row & 3);        \
        Ap[i] = (Adecl) + (size_t)(m0 + row) * K + ks * 32 + kch * 8;            \
        Wp[i] = (Wdecl) + (size_t)(n0 + row) * K + ks * 32 + kch * 8;            \
    }

#define GEMM_KLOOP(Klim)                                                         \
    float4 w0[4], w1[4];                                                         \
    _Pragma("unroll")                                                            \
    for (int i = 0; i < 4; ++i) {                                                \
        w0[i] = *(const float4*)(Wp[i]);                                         \
        w1[i] = *(const float4*)(Wp[i] + 4);                                     \
    }                                                                            \
    for (int k0 = 0; k0 < (Klim); k0 += 64) {                                    \
        _Pragma("unroll")                                                        \
        for (int i = 0; i < 4; ++i) {                                            \
            bf16x8 wv;                                                           \
            wv[0]=(__bf16)w0[i].x; wv[1]=(__bf16)w0[i].y;                        \
            wv[2]=(__bf16)w0[i].z; wv[3]=(__bf16)w0[i].w;                        \
            wv[4]=(__bf16)w1[i].x; wv[5]=(__bf16)w1[i].y;                        \
            wv[6]=(__bf16)w1[i].z; wv[7]=(__bf16)w1[i].w;                        \
            *(bf16x8*)(Ws + (size_t)(tid + 256 * i) * 8) = wv;                   \
            gl_lds16(Ap[i] + k0, As + (size_t)(tid + 256 * i) * 8);              \
        }                                                                        \
        __syncthreads();                                                         \
        if (k0 + 64 < (Klim)) {                                                  \
            _Pragma("unroll")                                                    \
            for (int i = 0; i < 4; ++i) {                                        \
                w0[i] = *(const float4*)(Wp[i] + k0 + 64);                       \
                w1[i] = *(const float4*)(Wp[i] + k0 + 68);                       \
            }                                                                    \
        }                                                                        \
        _Pragma("unroll")                                                        \
        for (int ks = 0; ks < 2; ++ks) {                                         \
            bf16x8 a[4], b[4];                                                   \
            _Pragma("unroll")                                                    \
            for (int mt = 0; mt < 4; ++mt)                                       \
                a[mt] = *(const bf16x8*)(As + ks*4096 + (wr*64+mt*16+r)*32 + rc);\
            _Pragma("unroll")                                                    \
            for (int nt = 0; nt < 4; ++nt)                                       \
                b[nt] = *(const bf16x8*)(Ws + ks*4096 + (wc*64+nt*16+r)*32 + rc);\
            _Pragma("unroll")                                                    \
            for (int mt = 0; mt < 4; ++mt)                                       \
                _Pragma("unroll")                                                \
                for (int nt = 0; nt < 4; ++nt)                                   \
                    acc[mt][nt] = __builtin_amdgcn_mfma_f32_16x16x32_bf16(       \
                        a[mt], b[nt], acc[mt][nt], 0, 0, 0);                     \
        }                                                                        \
        __syncthreads();                                                         \
    }

// ---------------- direct GEMM: C[M,N] = A[M,K]*W[N,K]^T + bias, f32 W ----------------
template<int ACT>
__global__ __launch_bounds__(256)
void gemm_bt(const bf16* __restrict__ A, const float* __restrict__ W,
             const float* __restrict__ bias, bf16* __restrict__ C,
             int M, int N, int K)
{
    const int m0 = blockIdx.y * 128, n0 = blockIdx.x * 128;
    GEMM_PROLOGUE(A, W)
    GEMM_KLOOP(K)
#pragma unroll
    for (int nt = 0; nt < 4; ++nt) {
        int n = n0 + wc * 64 + nt * 16 + r;
        float bv = bias[n];
#pragma unroll
        for (int mt = 0; mt < 4; ++mt) {
#pragma unroll
            for (int e = 0; e < 4; ++e) {
                int m = m0 + wr * 64 + mt * 16 + quad * 4 + e;
                float v = acc[mt][nt][e] + bv;
                if (ACT == 1) v = fmaxf(v, 0.f);
                C[(size_t)m * N + n] = (bf16)v;
            }
        }
    }
}

// ---------------- split-K GEMM: Cacc += A*W^T (f32 atomic), f32 W ----------------
template<int SPLIT>
__global__ __launch_bounds__(256)
void gemm_bt_splitk(const bf16* __restrict__ A, const float* __restrict__ Wfull,
                    float* __restrict__ Cacc, int M, int N, int K)
{
    const int m0 = blockIdx.y * 128, n0 = blockIdx.x * 128;
    const int Kc = K / SPLIT;
    const bf16* Ab = A + (size_t)blockIdx.z * Kc;
    const float* W = Wfull + (size_t)blockIdx.z * Kc;
    GEMM_PROLOGUE(Ab, W)
    GEMM_KLOOP(Kc)
#pragma unroll
    for (int nt = 0; nt < 4; ++nt) {
        int n = n0 + wc * 64 + nt * 16 + r;
#pragma unroll
        for (int mt = 0; mt < 4; ++mt) {
#pragma unroll
            for (int e = 0; e < 4; ++e) {
                int m = m0 + wr * 64 + mt * 16 + quad * 4 + e;
                atomicAdd(&Cacc[(size_t)m * N + n], acc[mt][nt][e]);
            }
        }
    }
}

// ---------------- V transpose: qkv v-part [s][h*64+d] -> Vt[h*64+d][s] ----------------
__global__ __launch_bounds__(256)
void transpose_v(const bf16* __restrict__ qkv, bf16* __restrict__ Vt)
{
    __shared__ __bf16 t[64][66];
    const int s0 = blockIdx.x * 64, dm0 = blockIdx.y * 64;
    const int tid = threadIdx.x;
    const int sl = tid >> 2, dc = (tid & 3) * 16;
    const bf16* src = qkv + (size_t)(s0 + sl) * 3072 + 2048 + dm0 + dc;
    bf16x8 v0 = *(const bf16x8*)(src);
    bf16x8 v1 = *(const bf16x8*)(src + 8);
#pragma unroll
    for (int j = 0; j < 8; ++j) { t[sl][dc + j] = v0[j]; t[sl][dc + 8 + j] = v1[j]; }
    __syncthreads();
    const int dl = tid >> 2, sc = (tid & 3) * 16;
    bf16x8 o0, o1;
#pragma unroll
    for (int j = 0; j < 8; ++j) { o0[j] = t[sc + j][dl]; o1[j] = t[sc + 8 + j][dl]; }
    bf16* dst = Vt + (size_t)(dm0 + dl) * SEQ + s0 + sc;
    *(bf16x8*)(dst) = o0;
    *(bf16x8*)(dst + 8) = o1;
}

// ---------------- banded flash attention with MFMA ----------------
__global__ __launch_bounds__(256)
void attn_mfma(const bf16* __restrict__ qkv, const bf16* __restrict__ Vt,
               bf16* __restrict__ o)
{
    __shared__ __align__(16) __bf16 Plds[4][16 * 40];
    const int tid = threadIdx.x, lane = tid & 63, w = tid >> 6;
    const int h = blockIdx.x & 15;
    const int qw = (blockIdx.x >> 4) * 64 + w * 16;
    const int r = lane & 15, quad = lane >> 4;
    __bf16* P = Plds[w];

    bf16x8 qa[2];
    {
        const bf16* qrow = qkv + (size_t)(qw + r) * 3072 + h * 64 + quad * 8;
#pragma unroll
        for (int c = 0; c < 2; ++c) {
            bf16x8 t = *(const bf16x8*)(qrow + c * 32);
#pragma unroll
            for (int j = 0; j < 8; ++j) qa[c][j] = (__bf16)((float)t[j] * 0.125f);
        }
    }

    bf16x8 ones;
#pragma unroll
    for (int j = 0; j < 8; ++j) ones[j] = (__bf16)1.0f;

    f32x4 acc[4];
#pragma unroll
    for (int d = 0; d < 4; ++d) acc[d] = (f32x4){0.f, 0.f, 0.f, 0.f};
    float m_run[4], l_run[4];
#pragma unroll
    for (int e = 0; e < 4; ++e) { m_run[e] = -1e30f; l_run[e] = 0.f; }

    int jmin = qw - (WINDOW - 1); if (jmin < 0) jmin = 0;
    int jmax = qw + 15 + (WINDOW - 1); if (jmax > SEQ - 1) jmax = SEQ - 1;

    for (int kt = jmin & ~31; kt <= jmax; kt += 32) {
        f32x4 S[2];
#pragma unroll
        for (int c = 0; c < 2; ++c) {
            const bf16* krow = qkv + (size_t)(kt + 16 * c + r) * 3072 + 1024 + h * 64 + quad * 8;
            bf16x8 kb0 = *(const bf16x8*)(krow);
            bf16x8 kb1 = *(const bf16x8*)(krow + 32);
            f32x4 s = (f32x4){0.f, 0.f, 0.f, 0.f};
            s = __builtin_amdgcn_mfma_f32_16x16x32_bf16(qa[0], kb0, s, 0, 0, 0);
            s = __builtin_amdgcn_mfma_f32_16x16x32_bf16(qa[1], kb1, s, 0, 0, 0);
            S[c] = s;
        }
#pragma unroll
        for (int c = 0; c < 2; ++c)
#pragma unroll
            for (int e = 0; e < 4; ++e) {
                int j = kt + 16 * c + r;
                int i = qw + quad * 4 + e;
                bool valid = (unsigned)(j - i + (WINDOW - 1)) <= (unsigned)(2 * WINDOW - 2);
                S[c][e] = valid ? S[c][e] : -1e30f;
            }
        float alpha[4], mnew[4];
#pragma unroll
        for (int e = 0; e < 4; ++e) {
            float v = fmaxf(S[0][e], S[1][e]);
#pragma unroll
            for (int off = 1; off <= 8; off <<= 1) v = fmaxf(v, __shfl_xor(v, off, 64));
            mnew[e] = fmaxf(m_run[e], v);
            alpha[e] = __expf(m_run[e] - mnew[e]);
            m_run[e] = mnew[e];
        }
#pragma unroll
        for (int c = 0; c < 2; ++c)
#pragma unroll
            for (int e = 0; e < 4; ++e) {
                float p = __expf(S[c][e] - mnew[e]);
                p = (S[c][e] <= -1e29f) ? 0.f : p;
                P[(quad * 4 + e) * 40 + 16 * c + r] = (__bf16)p;
            }
        bf16x8 pa = *(const bf16x8*)(P + r * 40 + quad * 8);
#pragma unroll
        for (int d = 0; d < 4; ++d)
#pragma unroll
            for (int e = 0; e < 4; ++e) acc[d][e] *= alpha[e];
        f32x4 ls = (f32x4){0.f, 0.f, 0.f, 0.f};
        ls = __builtin_amdgcn_mfma_f32_16x16x32_bf16(pa, ones, ls, 0, 0, 0);
#pragma unroll
        for (int e = 0; e < 4; ++e) l_run[e] = l_run[e] * alpha[e] + ls[e];
#pragma unroll
        for (int d = 0; d < 4; ++d) {
            const bf16* vrow = Vt + (size_t)(h * 64 + 16 * d + r) * SEQ + kt + quad * 8;
            bf16x8 vb = *(const bf16x8*)(vrow);
            acc[d] = __builtin_amdgcn_mfma_f32_16x16x32_bf16(pa, vb, acc[d], 0, 0, 0);
        }
    }

#pragma unroll
    for (int d = 0; d < 4; ++d)
#pragma unroll
        for (int e = 0; e < 4; ++e) {
            int i = qw + quad * 4 + e;
            o[(size_t)i * DMODEL + h * 64 + 16 * d + r] = (bf16)(acc[d][e] / l_run[e]);
        }
}

// ---------------- residual + layernorm, delta = f32 acc + f32 bias ----------------
__global__ __launch_bounds__(256)
void ln_residual_f32(bf16* __restrict__ x, const float* __restrict__ accd,
                     const float* __restrict__ bias,
                     const float* __restrict__ gamma, const float* __restrict__ beta)
{
    const int s = blockIdx.x, tid = threadIdx.x;
    const int lane = tid & 63, wave = tid >> 6;
    __shared__ float red[8];
    float v[4];
    float sum = 0.f;
#pragma unroll
    for (int i = 0; i < 4; ++i) {
        int d = i * 256 + tid;
        v[i] = (float)x[(size_t)s * 1024 + d] + accd[(size_t)s * 1024 + d] + bias[d];
        sum += v[i];
    }
#pragma unroll
    for (int off = 32; off; off >>= 1) sum += __shfl_xor(sum, off, 64);
    if (lane == 0) red[wave] = sum;
    __syncthreads();
    float mu = (red[0] + red[1] + red[2] + red[3]) * (1.f / 1024.f);
    float sq = 0.f;
#pragma unroll
    for (int i = 0; i < 4; ++i) { float t = v[i] - mu; sq += t * t; }
#pragma unroll
    for (int off = 32; off; off >>= 1) sq += __shfl_xor(sq, off, 64);
    if (lane == 0) red[wave + 4] = sq;
    __syncthreads();
    float var = (red[4] + red[5] + red[6] + red[7]) * (1.f / 1024.f);
    float inv = rsqrtf(var + LN_EPS);
#pragma unroll
    for (int i = 0; i < 4; ++i) {
        int d = i * 256 + tid;
        x[(size_t)s * 1024 + d] = (bf16)((v[i] - mu) * inv * gamma[d] + beta[d]);
    }
}

// ---------------- residual + layernorm, delta = bf16 ----------------
__global__ __launch_bounds__(256)
void ln_residual(bf16* __restrict__ x, const bf16* __restrict__ delta,
                 const float* __restrict__ gamma, const float* __restrict__ beta)
{
    const int s = blockIdx.x, tid = threadIdx.x;
    const int lane = tid & 63, wave = tid >> 6;
    __shared__ float red[8];
    float v[4];
    float sum = 0.f;
#pragma unroll
    for (int i = 0; i < 4; ++i) {
        int d = i * 256 + tid;
        v[i] = (float)x[(size_t)s * 1024 + d] + (float)delta[(size_t)s * 1024 + d];
        sum += v[i];
    }
#pragma unroll
    for (int off = 32; off; off >>= 1) sum += __shfl_xor(sum, off, 64);
    if (lane == 0) red[wave] = sum;
    __syncthreads();
    float mu = (red[0] + red[1] + red[2] + red[3]) * (1.f / 1024.f);
    float sq = 0.f;
#pragma unroll
    for (int i = 0; i < 4; ++i) { float t = v[i] - mu; sq += t * t; }
#pragma unroll
    for (int off = 32; off; off >>= 1) sq += __shfl_xor(sq, off, 64);
    if (lane == 0) red[wave + 4] = sq;
    __syncthreads();
    float var = (red[4] + red[5] + red[6] + red[7]) * (1.f / 1024.f);
    float inv = rsqrtf(var + LN_EPS);
#pragma unroll
    for (int i = 0; i < 4; ++i) {
        int d = i * 256 + tid;
        x[(size_t)s * 1024 + d] = (bf16)((v[i] - mu) * inv * gamma[d] + beta[d]);
    }
}

// ---------------- decoder: logits + log_softmax ----------------
__global__ __launch_bounds__(256)
void decoder(const bf16* __restrict__ x, const float* __restrict__ Wdec,
             const float* __restrict__ bdec, float* __restrict__ out)
{
    const int s = blockIdx.x * 4 + (threadIdx.x >> 6);
    const int lane = threadIdx.x & 63;
    float a0 = 0.f, a1 = 0.f, a2 = 0.f;
    for (int d = lane; d < 1024; d += 64) {
        float xv = (float)x[(size_t)s * 1024 + d];
        a0 += xv * Wdec[d];
        a1 += xv * Wdec[1024 + d];
        a2 += xv * Wdec[2048 + d];
    }
#pragma unroll
    for (int off = 32; off; off >>= 1) {
        a0 += __shfl_xor(a0, off, 64);
        a1 += __shfl_xor(a1, off, 64);
        a2 += __shfl_xor(a2, off, 64);
    }
    if (lane == 0) {
        float z0 = a0 + bdec[0];
        float z1 = a1 + bdec[1];
        float z2 = a2 + bdec[2];
        float mx = fmaxf(z0, fmaxf(z1, z2));
        float lse = mx + logf(__expf(z0 - mx) + __expf(z1 - mx) + __expf(z2 - mx));
        out[s * 3 + 0] = z0 - lse;
        out[s * 3 + 1] = z1 - lse;
        out[s * 3 + 2] = z2 - lse;
    }
}

extern "C" void kernel_launch(void* const* d_in, const int* in_sizes, int n_in,
                              void* d_out, int out_size, void* d_ws, size_t ws_size,
                              hipStream_t stream)
{
    const float* X    = (const float*)d_in[0];
    const float* Wqkv = (const float*)d_in[1];
    const float* bqkv = (const float*)d_in[2];
    const float* Wo   = (const float*)d_in[3];
    const float* bo   = (const float*)d_in[4];
    const float* ln1g = (const float*)d_in[5];
    const float* ln1b = (const float*)d_in[6];
    const float* W1   = (const float*)d_in[7];
    const float* b1   = (const float*)d_in[8];
    const float* W2   = (const float*)d_in[9];
    const float* b2   = (const float*)d_in[10];
    const float* ln2g = (const float*)d_in[11];
    const float* ln2b = (const float*)d_in[12];
    const float* Wdec = (const float*)d_in[13];
    const float* bdec = (const float*)d_in[14];

    // workspace (bf16 elems): x[2M] | buf[8M]=qkv6M/ao2M (reused as h) | tmp[2M]=Vt
    //                         accf: 2M f32 split-K accumulator
    bf16* ws   = (bf16*)d_ws;
    bf16* x    = ws;                                  // 2M
    bf16* buf  = x   + (size_t)SEQ * DMODEL;          // 8M
    bf16* qkv  = buf;
    bf16* ao   = buf + (size_t)SEQ * 3 * DMODEL;
    bf16* h    = buf;
    bf16* tmp  = buf + (size_t)SEQ * DFF;             // 2M (Vt)
    bf16* Vt   = tmp;
    float* accf = (float*)(tmp + (size_t)SEQ * DMODEL);   // 2M f32 (8 MB)

    add_pe<<<(SEQ * DMODEL) / 256, 256, 0, stream>>>(X, x);

    for (int l = 0; l < 4; ++l) {
        // QKV projection (direct, fused f32-W conversion)
        gemm_bt<0><<<dim3(3072 / 128, SEQ / 128), 256, 0, stream>>>(
            x, Wqkv + (size_t)l * 3072 * 1024, bqkv + l * 3072, qkv, SEQ, 3072, 1024);
        // banded flash attention
        transpose_v<<<dim3(SEQ / 64, DMODEL / 64), 256, 0, stream>>>(qkv, Vt);
        attn_mfma<<<(SEQ / 64) * NHEAD, 256, 0, stream>>>(qkv, Vt, ao);
        // O projection (split-K=4, f32 atomic; bias folded into LN)
        zero_f32<<<(SEQ * DMODEL / 4) / 256, 256, 0, stream>>>((float4*)accf);
        gemm_bt_splitk<4><<<dim3(1024 / 128, SEQ / 128, 4), 256, 0, stream>>>(
            ao, Wo + (size_t)l * 1024 * 1024, accf, SEQ, 1024, 1024);
        ln_residual_f32<<<SEQ, 256, 0, stream>>>(x, accf, bo + l * 1024,
                                                 ln1g + l * 1024, ln1b + l * 1024);
        // FF1 (relu, direct) — h overwrites qkv/ao region
        gemm_bt<1><<<dim3(4096 / 128, SEQ / 128), 256, 0, stream>>>(
            x, W1 + (size_t)l * 4096 * 1024, b1 + l * 4096, h, SEQ, 4096, 1024);
        // FF2 (split-K=4, f32 atomic; bias folded into LN)
        zero_f32<<<(SEQ * DMODEL / 4) / 256, 256, 0, stream>>>((float4*)accf);
        gemm_bt_splitk<4><<<dim3(1024 / 128, SEQ / 128, 4), 256, 0, stream>>>(
            h, W2 + (size_t)l * 1024 * 4096, accf, SEQ, 1024, 4096);
        ln_residual_f32<<<SEQ, 256, 0, stream>>>(x, accf, b2 + l * 1024,
                                                 ln2g + l * 1024, ln2b + l * 1024);
    }

    decoder<<<SEQ / 4, 256, 0, stream>>>(x, Wdec, bdec, (float*)d_out);
}